// Round 5
// baseline (203.779 us; speedup 1.0000x reference)
//
#include <hip/hip_runtime.h>

// ---------------- types / helpers ----------------
using bf16x8 = __attribute__((ext_vector_type(8))) short;
using f32x4  = __attribute__((ext_vector_type(4))) float;

static __device__ inline unsigned short f2bf(float f) {
  unsigned int u = __float_as_uint(f);
  u += 0x7fffu + ((u >> 16) & 1u);          // round-to-nearest-even
  return (unsigned short)(u >> 16);
}
static __device__ inline unsigned int pk2(float a, float b) {
  return (unsigned int)f2bf(a) | ((unsigned int)f2bf(b) << 16);
}

// butterfly reductions across the 16-lane DPP row (row_ror 1,2,4,8)
#define ROW16_MAX(x) { \
  { int _t = __builtin_amdgcn_update_dpp(0, __float_as_int(x), 0x121, 0xf, 0xf, true); x = fmaxf(x, __int_as_float(_t)); } \
  { int _t = __builtin_amdgcn_update_dpp(0, __float_as_int(x), 0x122, 0xf, 0xf, true); x = fmaxf(x, __int_as_float(_t)); } \
  { int _t = __builtin_amdgcn_update_dpp(0, __float_as_int(x), 0x124, 0xf, 0xf, true); x = fmaxf(x, __int_as_float(_t)); } \
  { int _t = __builtin_amdgcn_update_dpp(0, __float_as_int(x), 0x128, 0xf, 0xf, true); x = fmaxf(x, __int_as_float(_t)); } }
#define ROW16_SUM(x) { \
  { int _t = __builtin_amdgcn_update_dpp(0, __float_as_int(x), 0x121, 0xf, 0xf, true); x += __int_as_float(_t); } \
  { int _t = __builtin_amdgcn_update_dpp(0, __float_as_int(x), 0x122, 0xf, 0xf, true); x += __int_as_float(_t); } \
  { int _t = __builtin_amdgcn_update_dpp(0, __float_as_int(x), 0x124, 0xf, 0xf, true); x += __int_as_float(_t); } \
  { int _t = __builtin_amdgcn_update_dpp(0, __float_as_int(x), 0x128, 0xf, 0xf, true); x += __int_as_float(_t); } }

// ---------------- kernel 0: weight prep (transpose -> bf16) ----------------
__global__ __launch_bounds__(256) void prep_kernel(
    const float* __restrict__ Wq, const float* __restrict__ Wk, const float* __restrict__ Wv,
    const float* __restrict__ Wo, const float* __restrict__ bq, const float* __restrict__ bk,
    const float* __restrict__ bv,
    unsigned short* __restrict__ Wt, unsigned short* __restrict__ Wot, float* __restrict__ bqkv)
{
  int idx = blockIdx.x * 256 + threadIdx.x;
  if (idx < 192 * 1024) {
    int n = idx >> 10, k = idx & 1023;
    const float* W = (n < 64) ? Wq : (n < 128) ? Wk : Wv;
    Wt[idx] = f2bf(W[k * 64 + (n & 63)]);
  } else if (idx < 192 * 1024 + 1024 * 64) {
    int j = idx - 192 * 1024;
    int n = j >> 6, k = j & 63;
    Wot[j] = f2bf(Wo[k * 1024 + n]);
  } else if (idx < 192 * 1024 + 1024 * 64 + 192) {
    int n = idx - (192 * 1024 + 1024 * 64);
    bqkv[n] = (n < 64) ? bq[n] : (n < 128) ? bk[n - 64] : bv[n - 128];
  }
}

// ---------------- kernel 1: QKV projection (streaming MFMA, no barriers) ----------------
// X [16384][1024] fp32, Wt [192][1024] bf16.
// Outputs: qkvB [16384][128] bf16 (q|k row-major), vT [8*64][2304] bf16 (v transposed,
// data at col 64+t, poison pads masked downstream by P=0).
// Block = 4 waves stacked over 64 rows, same 96 cols (B frags L1-shared). Grid 512.
__global__ __launch_bounds__(256) void qkv_gemm(
    const float* __restrict__ X, const unsigned short* __restrict__ Wt,
    const float* __restrict__ bqkv,
    unsigned short* __restrict__ qkvB, unsigned short* __restrict__ vT)
{
  __shared__ __align__(16) unsigned short Tr[4][16 * 104];
  int t = threadIdx.x, lane = t & 63, w = t >> 6;
  int col = lane & 15, quad = lane >> 4, q4 = quad * 4;
  int m0 = (blockIdx.x >> 1) * 64;
  int nb = (blockIdx.x & 1) * 96;
  int mrow = m0 + w * 16;

  f32x4 acc[6] = {};
  const float* aptr = X + (size_t)(mrow + col) * 1024 + quad * 8;
  const unsigned short* bptr = Wt + (size_t)(nb + col) * 1024 + quad * 8;

  #pragma unroll 2
  for (int kc = 0; kc < 32; ++kc) {
    float4 f0 = *(const float4*)(aptr);
    float4 f1 = *(const float4*)(aptr + 4);
    aptr += 32;
    union { bf16x8 v; uint4 u; } au;
    au.u = make_uint4(pk2(f0.x, f0.y), pk2(f0.z, f0.w), pk2(f1.x, f1.y), pk2(f1.z, f1.w));
    #pragma unroll
    for (int nt = 0; nt < 6; ++nt) {
      bf16x8 b = *(const bf16x8*)(bptr + (size_t)nt * 16 * 1024);
      acc[nt] = __builtin_amdgcn_mfma_f32_16x16x32_bf16(au.v, b, acc[nt], 0, 0, 0);
    }
    bptr += 32;
  }
  // bias
  #pragma unroll
  for (int nt = 0; nt < 6; ++nt) {
    float bb = bqkv[nb + nt * 16 + col];
    #pragma unroll
    for (int r = 0; r < 4; ++r) acc[nt][r] += bb;
  }
  unsigned short* Tw = &Tr[w][0];
  if (nb == 0) {
    // q + first half of k -> row-major cols 0..95 (LDS transpose, same-wave only)
    #pragma unroll
    for (int nt = 0; nt < 6; ++nt)
      #pragma unroll
      for (int r = 0; r < 4; ++r)
        Tw[(q4 + r) * 104 + nt * 16 + col] = f2bf(acc[nt][r]);
    int row = lane & 15, seg = lane >> 4;
    #pragma unroll
    for (int u = 0; u < 3; ++u) {
      uint4 d = *(const uint4*)(Tw + row * 104 + seg * 24 + u * 8);
      *(uint4*)(qkvB + (size_t)(mrow + row) * 128 + seg * 24 + u * 8) = d;
    }
  } else {
    // second half of k -> row-major cols 96..127
    #pragma unroll
    for (int nt = 0; nt < 2; ++nt)
      #pragma unroll
      for (int r = 0; r < 4; ++r)
        Tw[(q4 + r) * 104 + nt * 16 + col] = f2bf(acc[nt][r]);
    int row = lane & 15, seg = lane >> 4;
    {
      uint4 d = *(const uint4*)(Tw + row * 104 + seg * 8);
      *(uint4*)(qkvB + (size_t)(mrow + row) * 128 + 96 + seg * 8) = d;
    }
    // v tiles (local 2..5): lane's 4 acc values are 4 consecutive t at fixed p -> direct vT store
    int b = mrow >> 11, t0 = (mrow & 2047) + q4;
    #pragma unroll
    for (int nt = 2; nt < 6; ++nt) {
      int p = nt * 16 + col - 32;
      unsigned int lo = pk2(acc[nt][0], acc[nt][1]);
      unsigned int hi = pk2(acc[nt][2], acc[nt][3]);
      *(uint2*)(vT + (size_t)(b * 64 + p) * 2304 + 64 + t0) = make_uint2(lo, hi);
    }
  }
}

// ---------------- kernel 2: banded flash attention (32-row tiles, j-split waves) ----------------
// Exact: out-of-band exp underflows to 0; padding mask softmax-invariant.
// grid 512 (2 blocks/CU, 8 waves/CU). Q/K frags direct from bf16 qkvB; V staged by
// uint4 copy from vT. Waves: (sub = q-subtile, par = j-parity); shared row-max via LDS,
// O/l pairwise combine via LDS. 3 barriers total.
__global__ __launch_bounds__(256) void band_attn(
    const unsigned short* __restrict__ qkvB, const unsigned short* __restrict__ vT,
    const float* __restrict__ bias, unsigned short* __restrict__ attnB)
{
  __shared__ __align__(16) unsigned short Vt[64 * 200];
  __shared__ __align__(16) unsigned short Ps[4][16 * 104];
  __shared__ float Ocomb[2][16 * 68];
  __shared__ float mx[2][2][16];
  __shared__ float lx[2][16];
  __shared__ float biasL[132];

  int t = threadIdx.x, lane = t & 63, w = t >> 6;
  int col = lane & 15, quad = lane >> 4, q4 = quad * 4;
  int b = blockIdx.x >> 6;
  int i0 = (blockIdx.x & 63) * 32;
  int jw = i0 - 64;
  if (t < 129) biasL[t] = bias[1984 + t];
  { // stage V: 64 p-rows x 192 window cols (pads in-bounds; masked by P=0)
    int p = t >> 2, s4 = t & 3;
    const unsigned short* src = vT + (size_t)(b * 64 + p) * 2304 + 64 + jw + s4 * 48;
    unsigned short* dst = Vt + p * 200 + s4 * 48;
    #pragma unroll
    for (int u = 0; u < 6; ++u)
      *(uint4*)(dst + u * 8) = *(const uint4*)(src + u * 8);
  }
  __syncthreads();

  int sub = w >> 1, par = w & 1;
  int iq = i0 + sub * 16;
  int s_w = sub + par;                  // first j-tile (step 2)
  int n_w = (par == 0) ? 5 : 4;         // tiles this wave owns
  const unsigned short* rowbase = qkvB + ((size_t)(b << 11)) * 128;

  // Q frags (A-layout) direct from global
  const unsigned short* qr = rowbase + (size_t)(iq + col) * 128 + quad * 8;
  bf16x8 aq0 = *(const bf16x8*)(qr);
  bf16x8 aq1 = *(const bf16x8*)(qr + 32);

  // QK^T over owned tiles, K frags direct from global (clamped addr, masked later)
  f32x4 s[5];
  #pragma unroll
  for (int gi = 0; gi < 5; ++gi) {
    if (gi < n_w) {
      int g = s_w + 2 * gi;
      int jb = jw + 16 * g + col;
      int jc = jb < 0 ? 0 : (jb > 2047 ? 2047 : jb);
      const unsigned short* kr = rowbase + (size_t)jc * 128 + 64 + quad * 8;
      bf16x8 kb0 = *(const bf16x8*)(kr);
      bf16x8 kb1 = *(const bf16x8*)(kr + 32);
      f32x4 z = {};
      z = __builtin_amdgcn_mfma_f32_16x16x32_bf16(aq0, kb0, z, 0, 0, 0);
      s[gi] = __builtin_amdgcn_mfma_f32_16x16x32_bf16(aq1, kb1, z, 0, 0, 0);
    }
  }
  // mask + bias + partial row max
  float mrow[4] = {-3e38f, -3e38f, -3e38f, -3e38f};
  #pragma unroll
  for (int gi = 0; gi < 5; ++gi) {
    if (gi < n_w) {
      int g = s_w + 2 * gi;
      int jb = jw + 16 * g + col;
      #pragma unroll
      for (int r = 0; r < 4; ++r) {
        int bi = 16 * g + col - sub * 16 - q4 - r;    // 64 - (i-j)
        bool valid = (jb >= 0) & (jb < 2048) & (bi >= 0) & (bi <= 128);
        int bic = bi < 0 ? 0 : (bi > 128 ? 128 : bi);
        float sv = valid ? (s[gi][r] * 0.125f + biasL[bic]) : -3e38f;
        s[gi][r] = sv;
        mrow[r] = fmaxf(mrow[r], sv);
      }
    }
  }
  #pragma unroll
  for (int r = 0; r < 4; ++r) ROW16_MAX(mrow[r]);
  if (col == 0) {
    #pragma unroll
    for (int r = 0; r < 4; ++r) mx[sub][par][q4 + r] = mrow[r];
  }
  __syncthreads();
  float m4[4];
  #pragma unroll
  for (int r = 0; r < 4; ++r) m4[r] = fmaxf(mrow[r], mx[sub][1 - par][q4 + r]);

  // exp with combined max (no rescale needed), partial sums, P -> per-wave LDS
  unsigned short* Pw = &Ps[w][0];
  float lsum[4] = {0.f, 0.f, 0.f, 0.f};
  #pragma unroll
  for (int gi = 0; gi < 6; ++gi) {
    if (gi < n_w) {
      #pragma unroll
      for (int r = 0; r < 4; ++r) {
        float p = __expf(s[gi][r] - m4[r]);
        lsum[r] += p;
        Pw[(q4 + r) * 104 + gi * 16 + col] = f2bf(p);
      }
    } else {
      #pragma unroll
      for (int r = 0; r < 4; ++r) Pw[(q4 + r) * 104 + gi * 16 + col] = 0;
    }
  }
  #pragma unroll
  for (int r = 0; r < 4; ++r) ROW16_SUM(lsum[r]);

  // PV over owned tiles (Vt col offset per quad selects the right j-tile)
  int c_w = (par == 0) ? 3 : 2;
  f32x4 o[4] = {};
  #pragma unroll
  for (int kc = 0; kc < 3; ++kc) {
    if (kc < c_w) {
      bf16x8 pa = *(const bf16x8*)(Pw + col * 104 + kc * 32 + quad * 8);
      int vcol = 16 * s_w + 64 * kc + 32 * (quad >> 1) + 8 * (quad & 1);
      #pragma unroll
      for (int nt = 0; nt < 4; ++nt) {
        bf16x8 vb = *(const bf16x8*)(Vt + (nt * 16 + col) * 200 + vcol);
        o[nt] = __builtin_amdgcn_mfma_f32_16x16x32_bf16(pa, vb, o[nt], 0, 0, 0);
      }
    }
  }
  // pairwise combine
  if (par == 1) {
    #pragma unroll
    for (int nt = 0; nt < 4; ++nt)
      #pragma unroll
      for (int r = 0; r < 4; ++r)
        Ocomb[sub][(q4 + r) * 68 + nt * 16 + col] = o[nt][r];
    if (col == 0) {
      #pragma unroll
      for (int r = 0; r < 4; ++r) lx[sub][q4 + r] = lsum[r];
    }
  }
  __syncthreads();
  if (par == 0) {
    float rl[4];
    #pragma unroll
    for (int r = 0; r < 4; ++r) rl[r] = 1.0f / (lsum[r] + lx[sub][q4 + r]);
    #pragma unroll
    for (int nt = 0; nt < 4; ++nt)
      #pragma unroll
      for (int r = 0; r < 4; ++r) {
        float val = (o[nt][r] + Ocomb[sub][(q4 + r) * 68 + nt * 16 + col]) * rl[r];
        int arow = (b << 11) + iq + q4 + r;
        attnB[(size_t)arow * 64 + nt * 16 + col] = f2bf(val);
      }
  }
}

// ---------------- kernel 3: output projection (streaming MFMA, no LDS/barriers) ----------------
// attnB [16384][64] bf16 @ Wot[n][k] -> out [16384][1024] fp32 + bo. Grid 2048, 32 waves/CU.
__global__ __launch_bounds__(256) void out_gemm(
    const unsigned short* __restrict__ attnB, const unsigned short* __restrict__ Wot,
    const float* __restrict__ bo, float* __restrict__ out)
{
  int t = threadIdx.x, lane = t & 63, w = t >> 6;
  int col = lane & 15, quad = lane >> 4, q4 = quad * 4;
  int m0 = (blockIdx.x >> 1) * 16;
  int n0 = (blockIdx.x & 1) * 512 + w * 128;
  const unsigned short* ar = attnB + (size_t)(m0 + col) * 64 + quad * 8;
  bf16x8 a0 = *(const bf16x8*)(ar);
  bf16x8 a1 = *(const bf16x8*)(ar + 32);
  f32x4 acc[8] = {};
  #pragma unroll
  for (int nt = 0; nt < 8; ++nt) {
    const unsigned short* br = Wot + (size_t)(n0 + nt * 16 + col) * 64 + quad * 8;
    bf16x8 b0 = *(const bf16x8*)(br);
    bf16x8 b1 = *(const bf16x8*)(br + 32);
    acc[nt] = __builtin_amdgcn_mfma_f32_16x16x32_bf16(a0, b0, acc[nt], 0, 0, 0);
    acc[nt] = __builtin_amdgcn_mfma_f32_16x16x32_bf16(a1, b1, acc[nt], 0, 0, 0);
  }
  #pragma unroll
  for (int nt = 0; nt < 8; ++nt) {
    int nn = n0 + nt * 16 + col;
    float bb = bo[nn];
    #pragma unroll
    for (int r = 0; r < 4; ++r)
      out[(size_t)(m0 + q4 + r) * 1024 + nn] = acc[nt][r] + bb;
  }
}

// ---------------- launch ----------------
extern "C" void kernel_launch(void* const* d_in, const int* in_sizes, int n_in,
                              void* d_out, int out_size, void* d_ws, size_t ws_size,
                              hipStream_t stream) {
  const float* X    = (const float*)d_in[0];
  // d_in[1] = attention_mask: per-row constant shift -> softmax-invariant, unused
  const float* Wq   = (const float*)d_in[2];
  const float* bq   = (const float*)d_in[3];
  const float* Wk   = (const float*)d_in[4];
  const float* bk   = (const float*)d_in[5];
  const float* Wv   = (const float*)d_in[6];
  const float* bv   = (const float*)d_in[7];
  const float* Wo   = (const float*)d_in[8];
  const float* bo   = (const float*)d_in[9];
  const float* bias = (const float*)d_in[10];
  float* out = (float*)d_out;
  char* ws = (char*)d_ws;
  unsigned short* qkvB = (unsigned short*)(ws);              // 16384*128*2 = 4,194,304
  unsigned short* vT   = (unsigned short*)(ws + 4194304);    // 512*2304*2  = 2,359,296
  unsigned short* attn = (unsigned short*)(ws + 6553600);    // 16384*64*2  = 2,097,152
  unsigned short* Wt   = (unsigned short*)(ws + 8650752);    // 192*1024*2  =   393,216
  unsigned short* Wot  = (unsigned short*)(ws + 9043968);    // 1024*64*2   =   131,072
  float*          bqkv = (float*)(ws + 9175040);             // 192*4

  prep_kernel<<<1025, 256, 0, stream>>>(Wq, Wk, Wv, Wo, bq, bk, bv, Wt, Wot, bqkv);
  qkv_gemm<<<512, 256, 0, stream>>>(X, Wt, bqkv, qkvB, vT);
  band_attn<<<512, 256, 0, stream>>>(qkvB, vT, bias, attn);
  out_gemm<<<2048, 256, 0, stream>>>(attn, Wot, bo, out);
}

// Round 6
// 198.666 us; speedup vs baseline: 1.0257x; 1.0257x over previous
//
#include <hip/hip_runtime.h>

// ---------------- types / helpers ----------------
using bf16x8 = __attribute__((ext_vector_type(8))) short;
using f32x4  = __attribute__((ext_vector_type(4))) float;

static __device__ inline unsigned short f2bf(float f) {
  unsigned int u = __float_as_uint(f);
  u += 0x7fffu + ((u >> 16) & 1u);          // round-to-nearest-even
  return (unsigned short)(u >> 16);
}
static __device__ inline unsigned int pk2(float a, float b) {
  return (unsigned int)f2bf(a) | ((unsigned int)f2bf(b) << 16);
}

// butterfly reductions across the 16-lane DPP row (row_ror 1,2,4,8)
#define ROW16_MAX(x) { \
  { int _t = __builtin_amdgcn_update_dpp(0, __float_as_int(x), 0x121, 0xf, 0xf, true); x = fmaxf(x, __int_as_float(_t)); } \
  { int _t = __builtin_amdgcn_update_dpp(0, __float_as_int(x), 0x122, 0xf, 0xf, true); x = fmaxf(x, __int_as_float(_t)); } \
  { int _t = __builtin_amdgcn_update_dpp(0, __float_as_int(x), 0x124, 0xf, 0xf, true); x = fmaxf(x, __int_as_float(_t)); } \
  { int _t = __builtin_amdgcn_update_dpp(0, __float_as_int(x), 0x128, 0xf, 0xf, true); x = fmaxf(x, __int_as_float(_t)); } }
#define ROW16_SUM(x) { \
  { int _t = __builtin_amdgcn_update_dpp(0, __float_as_int(x), 0x121, 0xf, 0xf, true); x += __int_as_float(_t); } \
  { int _t = __builtin_amdgcn_update_dpp(0, __float_as_int(x), 0x122, 0xf, 0xf, true); x += __int_as_float(_t); } \
  { int _t = __builtin_amdgcn_update_dpp(0, __float_as_int(x), 0x124, 0xf, 0xf, true); x += __int_as_float(_t); } \
  { int _t = __builtin_amdgcn_update_dpp(0, __float_as_int(x), 0x128, 0xf, 0xf, true); x += __int_as_float(_t); } }

// ---------------- kernel 0: weight prep (transpose -> bf16) ----------------
__global__ __launch_bounds__(256) void prep_kernel(
    const float* __restrict__ Wq, const float* __restrict__ Wk, const float* __restrict__ Wv,
    const float* __restrict__ Wo, const float* __restrict__ bq, const float* __restrict__ bk,
    const float* __restrict__ bv,
    unsigned short* __restrict__ Wt, unsigned short* __restrict__ Wot, float* __restrict__ bqkv)
{
  int idx = blockIdx.x * 256 + threadIdx.x;
  if (idx < 192 * 1024) {
    int n = idx >> 10, k = idx & 1023;
    const float* W = (n < 64) ? Wq : (n < 128) ? Wk : Wv;
    Wt[idx] = f2bf(W[k * 64 + (n & 63)]);
  } else if (idx < 192 * 1024 + 1024 * 64) {
    int j = idx - 192 * 1024;
    int n = j >> 6, k = j & 63;
    Wot[j] = f2bf(Wo[k * 1024 + n]);
  } else if (idx < 192 * 1024 + 1024 * 64 + 192) {
    int n = idx - (192 * 1024 + 1024 * 64);
    bqkv[n] = (n < 64) ? bq[n] : (n < 128) ? bk[n - 64] : bv[n - 128];
  }
}

// ---------------- kernel 1: QKV projection ----------------
// BM=16, whole K=1024 in LDS (one barrier), then barrier-free MFMA loop.
// Grid 1024 -> 4 blocks/CU = 16 waves/CU, waves slip freely.
// Wave w owns n-tiles {w (q), 4+w (k), 8+w (v)}.
// Outputs: qkvB [16384][128] bf16 (q|k) + vT [8*64][2304] bf16 (v transposed @ col 64+t).
__global__ __launch_bounds__(256) void qkv_gemm(
    const float* __restrict__ X, const unsigned short* __restrict__ Wt,
    const float* __restrict__ bqkv,
    unsigned short* __restrict__ qkvB, unsigned short* __restrict__ vT)
{
  __shared__ __align__(16) unsigned short As[16 * 1024];   // XOR-swizzled 16-elem chunks
  __shared__ __align__(16) unsigned short Ts[4][16 * 40];
  int t = threadIdx.x, lane = t & 63, w = t >> 6;
  int col = lane & 15, quad = lane >> 4, q4 = quad * 4;
  int m0 = blockIdx.x * 16;

  { // stage A: 16 rows x 1024 cols fp32 -> bf16, fully coalesced reads
    const float* base = X + (size_t)m0 * 1024;
    #pragma unroll
    for (int u = 0; u < 4; ++u) {
      int row = u * 4 + (t >> 6);
      int cb  = t & 63;                      // 16-float chunk id
      const float* s = base + row * 1024 + cb * 16;
      float4 f0 = *(const float4*)(s);
      float4 f1 = *(const float4*)(s + 4);
      float4 f2 = *(const float4*)(s + 8);
      float4 f3 = *(const float4*)(s + 12);
      int csw = (cb & ~15) | ((cb ^ row) & 15);
      unsigned short* d = As + row * 1024 + csw * 16;
      uint4 p0 = make_uint4(pk2(f0.x, f0.y), pk2(f0.z, f0.w), pk2(f1.x, f1.y), pk2(f1.z, f1.w));
      uint4 p1 = make_uint4(pk2(f2.x, f2.y), pk2(f2.z, f2.w), pk2(f3.x, f3.y), pk2(f3.z, f3.w));
      *(uint4*)d = p0;
      *(uint4*)(d + 8) = p1;
    }
  }
  __syncthreads();                           // the only barrier

  f32x4 acq = {}, ack = {}, acv = {};
  const unsigned short* pq = Wt + (size_t)(16 * w + col) * 1024 + quad * 8;
  const unsigned short* pk = pq + (size_t)64 * 1024;
  const unsigned short* pv = pq + (size_t)128 * 1024;
  #pragma unroll 4
  for (int kk = 0; kk < 32; ++kk) {
    int c = 2 * kk + (quad >> 1);
    int csw = (c & ~15) | ((c ^ col) & 15);
    bf16x8 a  = *(const bf16x8*)(As + col * 1024 + csw * 16 + (quad & 1) * 8);
    bf16x8 b0 = *(const bf16x8*)(pq);
    bf16x8 b1 = *(const bf16x8*)(pk);
    bf16x8 b2 = *(const bf16x8*)(pv);
    acq = __builtin_amdgcn_mfma_f32_16x16x32_bf16(a, b0, acq, 0, 0, 0);
    ack = __builtin_amdgcn_mfma_f32_16x16x32_bf16(a, b1, ack, 0, 0, 0);
    acv = __builtin_amdgcn_mfma_f32_16x16x32_bf16(a, b2, acv, 0, 0, 0);
    pq += 32; pk += 32; pv += 32;
  }

  float bqv = bqkv[16 * w + col];
  float bkv = bqkv[64 + 16 * w + col];
  float bvv = bqkv[128 + 16 * w + col];
  unsigned short* Tw = &Ts[w][0];
  #pragma unroll
  for (int r = 0; r < 4; ++r) {
    Tw[(q4 + r) * 40 + col]      = f2bf(acq[r] + bqv);
    Tw[(q4 + r) * 40 + 16 + col] = f2bf(ack[r] + bkv);
  }
  { // v: C-layout holds 4 consecutive t at fixed p -> direct transposed store
    int b = m0 >> 11, i0l = m0 & 2047;
    int p = 16 * w + col;
    unsigned int lo = pk2(acv[0] + bvv, acv[1] + bvv);
    unsigned int hi = pk2(acv[2] + bvv, acv[3] + bvv);
    *(uint2*)(vT + (size_t)(b * 64 + p) * 2304 + 64 + i0l + q4) = make_uint2(lo, hi);
  }
  { // q|k: wave-local LDS transpose -> row-major vector store
    int row = col;
    int cc = (quad < 2) ? quad * 8 : 16 + (quad - 2) * 8;
    uint4 d = *(const uint4*)(Tw + row * 40 + cc);
    int gcol = (quad < 2) ? 16 * w + (quad & 1) * 8 : 64 + 16 * w + (quad & 1) * 8;
    *(uint4*)(qkvB + (size_t)(m0 + row) * 128 + gcol) = d;
  }
}

// ---------------- kernel 2: banded flash attention (16-row tiles, 4-way j-split) ----------------
// Exact: out-of-band exp underflows to 0; padding mask softmax-invariant.
// Grid 1024 (4 blocks/CU, 16 waves/CU). Q/K frags direct from qkvB; V frags direct
// from vT (L2). Wave par owns j-tiles {par, par+4, par+8} (zero-padded P slots).
__global__ __launch_bounds__(256) void band_attn(
    const unsigned short* __restrict__ qkvB, const unsigned short* __restrict__ vT,
    const float* __restrict__ bias, unsigned short* __restrict__ attnB)
{
  __shared__ __align__(16) unsigned short Ps[4][16 * 72];
  __shared__ float Ocomb[3][16 * 68];
  __shared__ float mx[4][16];
  __shared__ float lx[4][16];
  __shared__ float biasL[160];

  int t = threadIdx.x, lane = t & 63, par = t >> 6;
  int col = lane & 15, quad = lane >> 4, q4 = quad * 4;
  int b = blockIdx.x >> 7;
  int i0 = (blockIdx.x & 127) * 16;
  int jw = i0 - 64;
  if (t < 160) biasL[t] = bias[1969 + t];
  const unsigned short* rowbase = qkvB + ((size_t)(b << 11)) * 128;

  // Q frags (A-layout) direct from global
  const unsigned short* qr = rowbase + (size_t)(i0 + col) * 128 + quad * 8;
  bf16x8 aq0 = *(const bf16x8*)(qr);
  bf16x8 aq1 = *(const bf16x8*)(qr + 32);

  int n_w = (par == 0) ? 3 : 2;             // owned tiles: par, par+4, (par==0: 8)
  f32x4 s[3];
  #pragma unroll
  for (int gi = 0; gi < 3; ++gi) {
    if (gi < n_w) {
      int g = par + 4 * gi;
      int jb = jw + 16 * g + col;
      int jc = jb < 0 ? 0 : (jb > 2047 ? 2047 : jb);
      const unsigned short* kr = rowbase + (size_t)jc * 128 + 64 + quad * 8;
      bf16x8 kb0 = *(const bf16x8*)(kr);
      bf16x8 kb1 = *(const bf16x8*)(kr + 32);
      f32x4 z = {};
      z = __builtin_amdgcn_mfma_f32_16x16x32_bf16(aq0, kb0, z, 0, 0, 0);
      s[gi] = __builtin_amdgcn_mfma_f32_16x16x32_bf16(aq1, kb1, z, 0, 0, 0);
    }
  }
  __syncthreads();                          // biasL ready

  float mrow[4] = {-3e38f, -3e38f, -3e38f, -3e38f};
  #pragma unroll
  for (int gi = 0; gi < 3; ++gi) {
    if (gi < n_w) {
      int g = par + 4 * gi;
      int jb = jw + 16 * g + col;
      #pragma unroll
      for (int r = 0; r < 4; ++r) {
        int imj = (i0 + q4 + r) - jb;       // i - j
        bool valid = (jb >= 0) & (jb < 2048) & (imj >= -64) & (imj <= 64);
        int si = 15 + 16 * g + col - q4 - r;   // in [0,158]
        float sv = valid ? (s[gi][r] * 0.125f + biasL[si]) : -3e38f;
        s[gi][r] = sv;
        mrow[r] = fmaxf(mrow[r], sv);
      }
    }
  }
  #pragma unroll
  for (int r = 0; r < 4; ++r) ROW16_MAX(mrow[r]);
  if (col == 0) {
    #pragma unroll
    for (int r = 0; r < 4; ++r) mx[par][q4 + r] = mrow[r];
  }
  __syncthreads();
  float m4[4];
  #pragma unroll
  for (int r = 0; r < 4; ++r)
    m4[r] = fmaxf(fmaxf(mx[0][q4 + r], mx[1][q4 + r]), fmaxf(mx[2][q4 + r], mx[3][q4 + r]));

  unsigned short* Pw = &Ps[par][0];
  float lsum[4] = {0.f, 0.f, 0.f, 0.f};
  #pragma unroll
  for (int slot = 0; slot < 4; ++slot) {
    if (slot < n_w) {
      #pragma unroll
      for (int r = 0; r < 4; ++r) {
        float p = __expf(s[slot][r] - m4[r]);
        lsum[r] += p;
        Pw[(q4 + r) * 72 + slot * 16 + col] = f2bf(p);
      }
    } else {
      #pragma unroll
      for (int r = 0; r < 4; ++r) Pw[(q4 + r) * 72 + slot * 16 + col] = 0;
    }
  }
  #pragma unroll
  for (int r = 0; r < 4; ++r) ROW16_SUM(lsum[r]);
  if (col == 0) {
    #pragma unroll
    for (int r = 0; r < 4; ++r) lx[par][q4 + r] = lsum[r];
  }

  // PV: P (16x64, zero-padded slots) x V-window; V frags straight from vT (L2).
  f32x4 o[4] = {};
  #pragma unroll
  for (int kc = 0; kc < 2; ++kc) {
    bf16x8 pa = *(const bf16x8*)(Pw + col * 72 + kc * 32 + quad * 8);
    int tile_c = par + 4 * (2 * kc + (quad >> 1));
    if (tile_c > 8) tile_c = 8;             // P=0 there; any valid addr OK
    int vcol = 64 + jw + tile_c * 16 + 8 * (quad & 1);
    #pragma unroll
    for (int nt = 0; nt < 4; ++nt) {
      bf16x8 vb = *(const bf16x8*)(vT + (size_t)(b * 64 + nt * 16 + col) * 2304 + vcol);
      o[nt] = __builtin_amdgcn_mfma_f32_16x16x32_bf16(pa, vb, o[nt], 0, 0, 0);
    }
  }
  if (par != 0) {
    #pragma unroll
    for (int nt = 0; nt < 4; ++nt)
      #pragma unroll
      for (int r = 0; r < 4; ++r)
        Ocomb[par - 1][(q4 + r) * 68 + nt * 16 + col] = o[nt][r];
  }
  __syncthreads();
  if (par == 0) {
    float rl[4];
    #pragma unroll
    for (int r = 0; r < 4; ++r)
      rl[r] = 1.0f / (lsum[r] + lx[1][q4 + r] + lx[2][q4 + r] + lx[3][q4 + r]);
    #pragma unroll
    for (int nt = 0; nt < 4; ++nt)
      #pragma unroll
      for (int r = 0; r < 4; ++r) {
        float val = (o[nt][r]
                     + Ocomb[0][(q4 + r) * 68 + nt * 16 + col]
                     + Ocomb[1][(q4 + r) * 68 + nt * 16 + col]
                     + Ocomb[2][(q4 + r) * 68 + nt * 16 + col]) * rl[r];
        int arow = (b << 11) + i0 + q4 + r;
        attnB[(size_t)arow * 64 + nt * 16 + col] = f2bf(val);
      }
  }
}

// ---------------- kernel 3: output projection (streaming MFMA, no LDS/barriers) ----------------
// attnB [16384][64] bf16 @ Wot[n][k] -> out [16384][1024] fp32 + bo. Grid 2048, 32 waves/CU.
__global__ __launch_bounds__(256) void out_gemm(
    const unsigned short* __restrict__ attnB, const unsigned short* __restrict__ Wot,
    const float* __restrict__ bo, float* __restrict__ out)
{
  int t = threadIdx.x, lane = t & 63, w = t >> 6;
  int col = lane & 15, quad = lane >> 4, q4 = quad * 4;
  int m0 = (blockIdx.x >> 1) * 16;
  int n0 = (blockIdx.x & 1) * 512 + w * 128;
  const unsigned short* ar = attnB + (size_t)(m0 + col) * 64 + quad * 8;
  bf16x8 a0 = *(const bf16x8*)(ar);
  bf16x8 a1 = *(const bf16x8*)(ar + 32);
  f32x4 acc[8] = {};
  #pragma unroll
  for (int nt = 0; nt < 8; ++nt) {
    const unsigned short* br = Wot + (size_t)(n0 + nt * 16 + col) * 64 + quad * 8;
    bf16x8 b0 = *(const bf16x8*)(br);
    bf16x8 b1 = *(const bf16x8*)(br + 32);
    acc[nt] = __builtin_amdgcn_mfma_f32_16x16x32_bf16(a0, b0, acc[nt], 0, 0, 0);
    acc[nt] = __builtin_amdgcn_mfma_f32_16x16x32_bf16(a1, b1, acc[nt], 0, 0, 0);
  }
  #pragma unroll
  for (int nt = 0; nt < 8; ++nt) {
    int nn = n0 + nt * 16 + col;
    float bb = bo[nn];
    #pragma unroll
    for (int r = 0; r < 4; ++r)
      out[(size_t)(m0 + q4 + r) * 1024 + nn] = acc[nt][r] + bb;
  }
}

// ---------------- launch ----------------
extern "C" void kernel_launch(void* const* d_in, const int* in_sizes, int n_in,
                              void* d_out, int out_size, void* d_ws, size_t ws_size,
                              hipStream_t stream) {
  const float* X    = (const float*)d_in[0];
  // d_in[1] = attention_mask: per-row constant shift -> softmax-invariant, unused
  const float* Wq   = (const float*)d_in[2];
  const float* bq   = (const float*)d_in[3];
  const float* Wk   = (const float*)d_in[4];
  const float* bk   = (const float*)d_in[5];
  const float* Wv   = (const float*)d_in[6];
  const float* bv   = (const float*)d_in[7];
  const float* Wo   = (const float*)d_in[8];
  const float* bo   = (const float*)d_in[9];
  const float* bias = (const float*)d_in[10];
  float* out = (float*)d_out;
  char* ws = (char*)d_ws;
  unsigned short* qkvB = (unsigned short*)(ws);              // 16384*128*2 = 4,194,304
  unsigned short* vT   = (unsigned short*)(ws + 4194304);    // 512*2304*2  = 2,359,296
  unsigned short* attn = (unsigned short*)(ws + 6553600);    // 16384*64*2  = 2,097,152
  unsigned short* Wt   = (unsigned short*)(ws + 8650752);    // 192*1024*2  =   393,216
  unsigned short* Wot  = (unsigned short*)(ws + 9043968);    // 1024*64*2   =   131,072
  float*          bqkv = (float*)(ws + 9175040);             // 192*4

  prep_kernel<<<1025, 256, 0, stream>>>(Wq, Wk, Wv, Wo, bq, bk, bv, Wt, Wot, bqkv);
  qkv_gemm<<<1024, 256, 0, stream>>>(X, Wt, bqkv, qkvB, vT);
  band_attn<<<1024, 256, 0, stream>>>(qkvB, vT, bias, attn);
  out_gemm<<<2048, 256, 0, stream>>>(attn, Wot, bo, out);
}